// Round 1
// baseline (583.023 us; speedup 1.0000x reference)
//
#include <hip/hip_runtime.h>
#include <math.h>

#define BB    256      // batch
#define DIN   512
#define HD    512
#define DOUT  10
#define NS    32       // samples
#define NIDX  2560     // BB*DOUT
#define MAXIT 10
#define CG_EPS 1e-12f

// ---------------- reduction helpers ----------------
__device__ __forceinline__ float wave_red(float v){
  #pragma unroll
  for (int off = 32; off > 0; off >>= 1) v += __shfl_down(v, off, 64);
  return v;  // lane 0 holds total
}

// ---------------- forward: h, G ----------------
// z = x @ W1 + b1 ; h = tanh(z) ; G = 1-h^2.  grid (8,4), 256 thr, 64x64 tile
__global__ __launch_bounds__(256) void k_gemm_z(
    const float* __restrict__ x, const float* __restrict__ W1,
    const float* __restrict__ b1, float* __restrict__ h, float* __restrict__ G)
{
  __shared__ __align__(16) float Al[16][68];
  __shared__ __align__(16) float Bl[16][64];
  const int tid = threadIdx.x;
  const int m0 = blockIdx.y * 64, n0 = blockIdx.x * 64;
  const int tx = tid & 15, ty = tid >> 4;
  float acc[4][4] = {};
  for (int k0 = 0; k0 < DIN; k0 += 16){
    {
      int m = tid >> 2, kk = (tid & 3) << 2;
      float4 a = *(const float4*)(x + (size_t)(m0+m)*DIN + k0 + kk);
      Al[kk+0][m]=a.x; Al[kk+1][m]=a.y; Al[kk+2][m]=a.z; Al[kk+3][m]=a.w;
    }
    {
      int kk = tid >> 4, n = (tid & 15) << 2;
      *(float4*)&Bl[kk][n] = *(const float4*)(W1 + (size_t)(k0+kk)*HD + n0 + n);
    }
    __syncthreads();
    #pragma unroll
    for (int kk = 0; kk < 16; kk++){
      float4 av = *(const float4*)&Al[kk][ty<<2];
      float4 bv = *(const float4*)&Bl[kk][tx<<2];
      float aa[4]={av.x,av.y,av.z,av.w}, bb[4]={bv.x,bv.y,bv.z,bv.w};
      #pragma unroll
      for (int i=0;i<4;i++)
        #pragma unroll
        for (int j=0;j<4;j++) acc[i][j] += aa[i]*bb[j];
    }
    __syncthreads();
  }
  float4 b4 = *(const float4*)&b1[n0 + (tx<<2)];
  float bbv[4] = {b4.x,b4.y,b4.z,b4.w};
  #pragma unroll
  for (int i=0;i<4;i++){
    int m = m0 + (ty<<2) + i;
    float hh[4], gg[4];
    #pragma unroll
    for (int j=0;j<4;j++){ float t = tanhf(acc[i][j] + bbv[j]); hh[j]=t; gg[j]=1.0f-t*t; }
    *(float4*)&h[(size_t)m*HD + n0 + (tx<<2)] = make_float4(hh[0],hh[1],hh[2],hh[3]);
    *(float4*)&G[(size_t)m*HD + n0 + (tx<<2)] = make_float4(gg[0],gg[1],gg[2],gg[3]);
  }
}

// ---------------- Kx = x x^T + 1 ; Kh = h h^T + 1 ----------------
// grid (4,4,2): z=0 -> Kx from x, z=1 -> Kh from h.  C = A A^T (NT)
__global__ __launch_bounds__(256) void k_gemm_kxkh(
    const float* __restrict__ x, const float* __restrict__ h,
    float* __restrict__ Kx, float* __restrict__ Kh)
{
  __shared__ __align__(16) float Al[16][68];
  __shared__ __align__(16) float Bl[16][68];
  const int tid = threadIdx.x;
  const float* A = blockIdx.z ? h : x;
  float* C = blockIdx.z ? Kh : Kx;
  const int m0 = blockIdx.y * 64, n0 = blockIdx.x * 64;
  const int tx = tid & 15, ty = tid >> 4;
  float acc[4][4] = {};
  for (int k0 = 0; k0 < DIN; k0 += 16){
    {
      int m = tid >> 2, kk = (tid & 3) << 2;
      float4 a = *(const float4*)(A + (size_t)(m0+m)*DIN + k0 + kk);
      Al[kk+0][m]=a.x; Al[kk+1][m]=a.y; Al[kk+2][m]=a.z; Al[kk+3][m]=a.w;
      float4 b = *(const float4*)(A + (size_t)(n0+m)*DIN + k0 + kk);
      Bl[kk+0][m]=b.x; Bl[kk+1][m]=b.y; Bl[kk+2][m]=b.z; Bl[kk+3][m]=b.w;
    }
    __syncthreads();
    #pragma unroll
    for (int kk = 0; kk < 16; kk++){
      float4 av = *(const float4*)&Al[kk][ty<<2];
      float4 bv = *(const float4*)&Bl[kk][tx<<2];
      float aa[4]={av.x,av.y,av.z,av.w}, bb[4]={bv.x,bv.y,bv.z,bv.w};
      #pragma unroll
      for (int i=0;i<4;i++)
        #pragma unroll
        for (int j=0;j<4;j++) acc[i][j] += aa[i]*bb[j];
    }
    __syncthreads();
  }
  #pragma unroll
  for (int i=0;i<4;i++){
    int m = m0 + (ty<<2) + i;
    *(float4*)&C[(size_t)m*BB + n0 + (tx<<2)] =
        make_float4(acc[i][0]+1.0f, acc[i][1]+1.0f, acc[i][2]+1.0f, acc[i][3]+1.0f);
  }
}

// ---------------- E[(b,o)][j] = G[b][j]*W2[j][o] ----------------
__global__ __launch_bounds__(256) void k_buildE(
    const float* __restrict__ G, const float* __restrict__ W2, float* __restrict__ E)
{
  int gid = blockIdx.x * 256 + threadIdx.x;   // 2560*128 lanes (f4 over j)
  int row = gid >> 7, j4 = (gid & 127) << 2;
  int b = row / 10, o = row - b * 10;
  float4 g = *(const float4*)&G[(size_t)b*HD + j4];
  *(float4*)&E[(size_t)row*HD + j4] = make_float4(
      g.x * W2[(j4+0)*DOUT + o], g.y * W2[(j4+1)*DOUT + o],
      g.z * W2[(j4+2)*DOUT + o], g.w * W2[(j4+3)*DOUT + o]);
}

// ---------------- M = Kx .* (E E^T) + delta_{oo'} Kh ----------------
// grid (40,40), 64x64 tiles, K=512
__global__ __launch_bounds__(256) void k_gemm_M(
    const float* __restrict__ E, const float* __restrict__ Kx,
    const float* __restrict__ Kh, float* __restrict__ Mmat)
{
  __shared__ __align__(16) float Al[16][68];
  __shared__ __align__(16) float Bl[16][68];
  const int tid = threadIdx.x;
  const int m0 = blockIdx.y * 64, n0 = blockIdx.x * 64;
  const int tx = tid & 15, ty = tid >> 4;
  float acc[4][4] = {};
  for (int k0 = 0; k0 < HD; k0 += 16){
    {
      int m = tid >> 2, kk = (tid & 3) << 2;
      float4 a = *(const float4*)(E + (size_t)(m0+m)*HD + k0 + kk);
      Al[kk+0][m]=a.x; Al[kk+1][m]=a.y; Al[kk+2][m]=a.z; Al[kk+3][m]=a.w;
      float4 b = *(const float4*)(E + (size_t)(n0+m)*HD + k0 + kk);
      Bl[kk+0][m]=b.x; Bl[kk+1][m]=b.y; Bl[kk+2][m]=b.z; Bl[kk+3][m]=b.w;
    }
    __syncthreads();
    #pragma unroll
    for (int kk = 0; kk < 16; kk++){
      float4 av = *(const float4*)&Al[kk][ty<<2];
      float4 bv = *(const float4*)&Bl[kk][tx<<2];
      float aa[4]={av.x,av.y,av.z,av.w}, bb[4]={bv.x,bv.y,bv.z,bv.w};
      #pragma unroll
      for (int i=0;i<4;i++)
        #pragma unroll
        for (int j=0;j<4;j++) acc[i][j] += aa[i]*bb[j];
    }
    __syncthreads();
  }
  int bi[4], oi[4], bj[4], oj[4];
  #pragma unroll
  for (int t=0;t<4;t++){
    int ri = m0 + (ty<<2) + t; bi[t] = ri/10; oi[t] = ri - bi[t]*10;
    int rj = n0 + (tx<<2) + t; bj[t] = rj/10; oj[t] = rj - bj[t]*10;
  }
  #pragma unroll
  for (int i=0;i<4;i++){
    float vv[4];
    #pragma unroll
    for (int j=0;j<4;j++){
      float v = Kx[(size_t)bi[i]*BB + bj[j]] * acc[i][j];
      if (oi[i] == oj[j]) v += Kh[(size_t)bi[i]*BB + bj[j]];
      vv[j] = v;
    }
    *(float4*)&Mmat[(size_t)(m0+(ty<<2)+i)*NIDX + n0 + (tx<<2)] =
        make_float4(vv[0],vv[1],vv[2],vv[3]);
  }
}

// ---------------- T[s] = (x @ eps_W1[s] + eps_b1[s]) * G  (batched NN) ----------------
// grid (8,4,32)
__global__ __launch_bounds__(256) void k_gemm_T(
    const float* __restrict__ x, const float* __restrict__ eW1,
    const float* __restrict__ eb1, const float* __restrict__ G,
    float* __restrict__ T)
{
  __shared__ __align__(16) float Al[16][68];
  __shared__ __align__(16) float Bl[16][64];
  const int tid = threadIdx.x;
  const int s = blockIdx.z;
  const int m0 = blockIdx.y * 64, n0 = blockIdx.x * 64;
  const float* Bsrc = eW1 + (size_t)s * DIN * HD;
  const int tx = tid & 15, ty = tid >> 4;
  float acc[4][4] = {};
  for (int k0 = 0; k0 < DIN; k0 += 16){
    {
      int m = tid >> 2, kk = (tid & 3) << 2;
      float4 a = *(const float4*)(x + (size_t)(m0+m)*DIN + k0 + kk);
      Al[kk+0][m]=a.x; Al[kk+1][m]=a.y; Al[kk+2][m]=a.z; Al[kk+3][m]=a.w;
    }
    {
      int kk = tid >> 4, n = (tid & 15) << 2;
      *(float4*)&Bl[kk][n] = *(const float4*)(Bsrc + (size_t)(k0+kk)*HD + n0 + n);
    }
    __syncthreads();
    #pragma unroll
    for (int kk = 0; kk < 16; kk++){
      float4 av = *(const float4*)&Al[kk][ty<<2];
      float4 bv = *(const float4*)&Bl[kk][tx<<2];
      float aa[4]={av.x,av.y,av.z,av.w}, bb[4]={bv.x,bv.y,bv.z,bv.w};
      #pragma unroll
      for (int i=0;i<4;i++)
        #pragma unroll
        for (int j=0;j<4;j++) acc[i][j] += aa[i]*bb[j];
    }
    __syncthreads();
  }
  float4 e4 = *(const float4*)&eb1[(size_t)s*HD + n0 + (tx<<2)];
  float eb[4] = {e4.x,e4.y,e4.z,e4.w};
  #pragma unroll
  for (int i=0;i<4;i++){
    int m = m0 + (ty<<2) + i;
    float4 g4 = *(const float4*)&G[(size_t)m*HD + n0 + (tx<<2)];
    float gg[4] = {g4.x,g4.y,g4.z,g4.w};
    float vv[4];
    #pragma unroll
    for (int j=0;j<4;j++) vv[j] = (acc[i][j] + eb[j]) * gg[j];
    *(float4*)&T[((size_t)s*BB + m)*HD + n0 + (tx<<2)] = make_float4(vv[0],vv[1],vv[2],vv[3]);
  }
}

// ---------------- out0 = h @ W2 + b2 ----------------
__global__ __launch_bounds__(256) void k_out0(
    const float* __restrict__ h, const float* __restrict__ W2,
    const float* __restrict__ b2, float* __restrict__ out0)
{
  int gid = blockIdx.x * 256 + threadIdx.x;  // 2560
  int b = gid / 10, o = gid - b * 10;
  const float* hr = h + (size_t)b * HD;
  float acc = b2[o];
  #pragma unroll 4
  for (int j = 0; j < HD; j++) acc += hr[j] * W2[j*DOUT + o];
  out0[gid] = acc;
}

// ---------------- b_s = T[s] @ W2 + h @ eps_W2[s] + eps_b2[s]  (layout [s][idx]) ----------------
__global__ __launch_bounds__(256) void k_bvec(
    const float* __restrict__ T, const float* __restrict__ W2,
    const float* __restrict__ h, const float* __restrict__ eW2,
    const float* __restrict__ eb2, float* __restrict__ bvec,
    float* __restrict__ rr0_part)
{
  __shared__ float wl[4];
  int gid = blockIdx.x * 256 + threadIdx.x;   // 81920; block covers a single s
  int s = gid / NIDX; int idx = gid - s * NIDX;
  int b = idx / 10, o = idx - b * 10;
  const float* Tr = T + ((size_t)s*BB + b) * HD;
  const float* hr = h + (size_t)b * HD;
  const float* ew = eW2 + (size_t)s * HD * DOUT + o;
  float acc = eb2[s*DOUT + o];
  #pragma unroll 4
  for (int j = 0; j < HD; j++)
    acc += Tr[j] * W2[j*DOUT + o] + hr[j] * ew[(size_t)j*DOUT];
  bvec[gid] = acc;
  float v = wave_red(acc * acc);
  if ((threadIdx.x & 63) == 0) wl[threadIdx.x >> 6] = v;
  __syncthreads();
  if (threadIdx.x == 0) rr0_part[blockIdx.x] = wl[0]+wl[1]+wl[2]+wl[3];
}

// ---------------- CG init ----------------
__global__ __launch_bounds__(256) void k_init(
    const float* __restrict__ bvec, const float* __restrict__ rr0_part,
    float* __restrict__ r, float* __restrict__ p, float* __restrict__ a,
    float* __restrict__ basis, float* __restrict__ rr_arr)
{
  int gid = blockIdx.x * 256 + threadIdx.x;
  int s = gid / NIDX;
  float rr0 = 0.f;
  #pragma unroll
  for (int i = 0; i < 10; i++) rr0 += rr0_part[s*10 + i];
  float bv = bvec[gid];
  r[gid] = bv; p[gid] = bv; a[gid] = 0.f;
  basis[gid] = bv / (sqrtf(rr0) + CG_EPS);
  #pragma unroll
  for (int j = 1; j <= MAXIT; j++) basis[(size_t)j*NS*NIDX + gid] = 0.f;
  if (threadIdx.x == 0) rr_arr[s] = rr0;
}

// ---------------- matvec: Ap_part[kc] = M[:, Kchunk] @ p ; pAp block partials ----------------
// grid (20 row-tiles of 128, 10 K-chunks of 256)
__global__ __launch_bounds__(256) void k_matvec(
    const float* __restrict__ Mmat, const float* __restrict__ pv,
    float* __restrict__ Ap_part, float* __restrict__ pAp_part)
{
  __shared__ __align__(16) float Ml[32][132];
  __shared__ __align__(16) float Pl[32][36];
  __shared__ float sred[32][33];
  const int tid = threadIdx.x;
  const int rt = blockIdx.x, kc = blockIdx.y;
  const int R0 = rt * 128, K0 = kc * 256;
  const int tx = tid & 7, ty = tid >> 3;
  float acc[4][4] = {};
  for (int k0 = K0; k0 < K0 + 256; k0 += 32){
    #pragma unroll
    for (int it = 0; it < 4; it++){
      int id = tid + it * 256;
      int rr = id >> 3, f4 = id & 7;
      float4 mv = *(const float4*)(Mmat + (size_t)(R0+rr)*NIDX + k0 + (f4<<2));
      Ml[(f4<<2)+0][rr]=mv.x; Ml[(f4<<2)+1][rr]=mv.y; Ml[(f4<<2)+2][rr]=mv.z; Ml[(f4<<2)+3][rr]=mv.w;
    }
    {
      int s = tid >> 3, kf = (tid & 7) << 2;
      float4 pvv = *(const float4*)(pv + (size_t)s*NIDX + k0 + kf);
      Pl[kf+0][s]=pvv.x; Pl[kf+1][s]=pvv.y; Pl[kf+2][s]=pvv.z; Pl[kf+3][s]=pvv.w;
    }
    __syncthreads();
    #pragma unroll
    for (int kk = 0; kk < 32; kk++){
      float4 mv = *(const float4*)&Ml[kk][ty<<2];
      float4 pvv = *(const float4*)&Pl[kk][tx<<2];
      float mm[4]={mv.x,mv.y,mv.z,mv.w}, pp[4]={pvv.x,pvv.y,pvv.z,pvv.w};
      #pragma unroll
      for (int i=0;i<4;i++)
        #pragma unroll
        for (int j=0;j<4;j++) acc[i][j] += mm[i]*pp[j];
    }
    __syncthreads();
  }
  #pragma unroll
  for (int j = 0; j < 4; j++){
    int s = (tx<<2) + j;
    float4 pvv = *(const float4*)(pv + (size_t)s*NIDX + R0 + (ty<<2));
    float ps = acc[0][j]*pvv.x + acc[1][j]*pvv.y + acc[2][j]*pvv.z + acc[3][j]*pvv.w;
    *(float4*)&Ap_part[((size_t)kc*NS + s)*NIDX + R0 + (ty<<2)] =
        make_float4(acc[0][j], acc[1][j], acc[2][j], acc[3][j]);
    sred[ty][s] = ps;
  }
  __syncthreads();
  if (tid < 32){
    float v = 0.f;
    #pragma unroll
    for (int t = 0; t < 32; t++) v += sred[t][tid];
    pAp_part[(size_t)(kc*20 + rt)*NS + tid] = v;
  }
}

// ---------------- CG step part 2: alpha, a/r update, Gram-Schmidt coeff partials ----------------
__global__ __launch_bounds__(256) void k_s2(
    const float* __restrict__ Ap_part, const float* __restrict__ pAp_part,
    const float* __restrict__ rr_arr, int k,
    const float* __restrict__ pv, float* __restrict__ av, float* __restrict__ rv,
    const float* __restrict__ basis, float* __restrict__ c_part)
{
  __shared__ float wl[4];
  __shared__ float cl[4][11];
  const int tid = threadIdx.x, bid = blockIdx.x;
  const int s = bid / 10;
  const int idx = (bid % 10) * 256 + tid;
  const size_t e = (size_t)s * NIDX + idx;
  // reduce pAp over 200 block partials (deterministic)
  float v = (tid < 200) ? pAp_part[(size_t)tid*NS + s] : 0.f;
  v = wave_red(v);
  const int w = tid >> 6;
  if ((tid & 63) == 0) wl[w] = v;
  __syncthreads();
  float pAp = wl[0]+wl[1]+wl[2]+wl[3];
  float alpha = rr_arr[k*NS + s] / (pAp + CG_EPS);
  float ap = 0.f;
  #pragma unroll
  for (int kc = 0; kc < 10; kc++) ap += Ap_part[((size_t)kc*NS + s)*NIDX + idx];
  float pvv = pv[e];
  av[e] += alpha * pvv;
  float rn = rv[e] - alpha * ap;
  rv[e] = rn;
  float cj[11];
  #pragma unroll
  for (int j = 0; j < 11; j++)
    cj[j] = wave_red(basis[(size_t)j*NS*NIDX + e] * rn);
  if ((tid & 63) == 0){
    #pragma unroll
    for (int j = 0; j < 11; j++) cl[w][j] = cj[j];
  }
  __syncthreads();
  if (tid < 11) c_part[bid*11 + tid] = cl[0][tid]+cl[1][tid]+cl[2][tid]+cl[3][tid];
}

// ---------------- CG step part 3: reorthogonalize, rr partials ----------------
__global__ __launch_bounds__(256) void k_s3(
    float* __restrict__ rv, const float* __restrict__ basis,
    const float* __restrict__ c_part, float* __restrict__ rr_part)
{
  __shared__ float wl[4];
  const int tid = threadIdx.x, bid = blockIdx.x;
  const int s = bid / 10;
  const size_t e = (size_t)s * NIDX + (bid % 10) * 256 + tid;
  float cj[11];
  #pragma unroll
  for (int j = 0; j < 11; j++){
    float c = 0.f;
    #pragma unroll
    for (int i = 0; i < 10; i++) c += c_part[(s*10 + i)*11 + j];
    cj[j] = c;
  }
  float rn = rv[e];
  #pragma unroll
  for (int j = 0; j < 11; j++) rn -= basis[(size_t)j*NS*NIDX + e] * cj[j];
  rv[e] = rn;
  float v = wave_red(rn * rn);
  if ((tid & 63) == 0) wl[tid >> 6] = v;
  __syncthreads();
  if (tid == 0) rr_part[bid] = wl[0]+wl[1]+wl[2]+wl[3];
}

// ---------------- CG step part 4: beta, p update, basis append ----------------
__global__ __launch_bounds__(256) void k_s4(
    float* __restrict__ pv, const float* __restrict__ rv, float* __restrict__ basis,
    const float* __restrict__ rr_part, float* __restrict__ rr_arr, int k)
{
  const int tid = threadIdx.x, bid = blockIdx.x;
  const int s = bid / 10;
  const size_t e = (size_t)s * NIDX + (bid % 10) * 256 + tid;
  float rrn = 0.f;
  #pragma unroll
  for (int i = 0; i < 10; i++) rrn += rr_part[s*10 + i];
  float beta = rrn / (rr_arr[k*NS + s] + CG_EPS);
  float rn = rv[e];
  pv[e] = rn + beta * pv[e];
  basis[(size_t)(k+1)*NS*NIDX + e] = rn / (sqrtf(rrn) + CG_EPS);
  if (tid == 0) rr_arr[(k+1)*NS + s] = rrn;
}

// ---------------- final: preds = out0 + si*b + (sk-si)*(M a) ----------------
__global__ __launch_bounds__(256) void k_final(
    const float* __restrict__ out0, const float* __restrict__ bvec,
    const float* __restrict__ Ma_part, const float* __restrict__ lp,
    const float* __restrict__ lsi, float* __restrict__ out)
{
  int gid = blockIdx.x * 256 + threadIdx.x;
  int s = gid / NIDX, idx = gid - s * NIDX;
  float sk = expf(-0.5f * lp[0]);
  float si = expf(lsi[0]);
  float ma = 0.f;
  #pragma unroll
  for (int kc = 0; kc < 10; kc++) ma += Ma_part[((size_t)kc*NS + s)*NIDX + idx];
  out[gid] = out0[idx] + si * bvec[gid] + (sk - si) * ma;
}

// ---------------- launch ----------------
extern "C" void kernel_launch(void* const* d_in, const int* in_sizes, int n_in,
                              void* d_out, int out_size, void* d_ws, size_t ws_size,
                              hipStream_t stream)
{
  const float* x   = (const float*)d_in[0];
  const float* W1  = (const float*)d_in[1];
  const float* b1  = (const float*)d_in[2];
  const float* W2  = (const float*)d_in[3];
  const float* b2  = (const float*)d_in[4];
  const float* eW1 = (const float*)d_in[5];
  const float* eb1 = (const float*)d_in[6];
  const float* eW2 = (const float*)d_in[7];
  const float* eb2 = (const float*)d_in[8];
  const float* lp  = (const float*)d_in[9];
  const float* lsi = (const float*)d_in[10];
  float* out = (float*)d_out;

  float* ws = (float*)d_ws;
  float* h        = ws;                       // 131072
  float* G        = h        + 131072;        // 131072
  float* Kx       = G        + 131072;        // 65536
  float* Kh       = Kx       + 65536;         // 65536
  float* E        = Kh       + 65536;         // 1310720
  float* Mmat     = E        + 1310720;       // 6553600
  float* T        = Mmat;                     // alias: T (4194304) dead before M is built
  float* out0     = Mmat     + 6553600;       // 2560
  float* bvec     = out0     + 2560;          // 81920
  float* rv       = bvec     + 81920;         // 81920
  float* pv       = rv       + 81920;         // 81920
  float* av       = pv       + 81920;         // 81920
  float* basis    = av       + 81920;         // 11*81920 = 901120
  float* Ap_part  = basis    + 901120;        // 10*81920 = 819200
  float* pAp_part = Ap_part  + 819200;        // 200*32 = 6400
  float* c_part   = pAp_part + 6400;          // 320*11 = 3520
  float* rr_part  = c_part   + 3520;          // 320
  float* rr0_part = rr_part  + 320;           // 320
  float* rr_arr   = rr0_part + 320;           // 11*32 = 352
  // total 10,319,008 floats = ~41.3 MB

  // setup
  k_gemm_z   <<<dim3(8,4),   256, 0, stream>>>(x, W1, b1, h, G);
  k_buildE   <<<1280,        256, 0, stream>>>(G, W2, E);
  k_gemm_kxkh<<<dim3(4,4,2), 256, 0, stream>>>(x, h, Kx, Kh);
  k_out0     <<<10,          256, 0, stream>>>(h, W2, b2, out0);
  k_gemm_T   <<<dim3(8,4,32),256, 0, stream>>>(x, eW1, eb1, G, T);
  k_bvec     <<<320,         256, 0, stream>>>(T, W2, h, eW2, eb2, bvec, rr0_part);
  k_gemm_M   <<<dim3(40,40), 256, 0, stream>>>(E, Kx, Kh, Mmat);  // overwrites T (dead)
  k_init     <<<320,         256, 0, stream>>>(bvec, rr0_part, rv, pv, av, basis, rr_arr);

  // 10 fixed CG steps with full reorthogonalization
  for (int k = 0; k < MAXIT; k++){
    k_matvec<<<dim3(20,10), 256, 0, stream>>>(Mmat, pv, Ap_part, pAp_part);
    k_s2    <<<320,         256, 0, stream>>>(Ap_part, pAp_part, rr_arr, k, pv, av, rv, basis, c_part);
    k_s3    <<<320,         256, 0, stream>>>(rv, basis, c_part, rr_part);
    k_s4    <<<320,         256, 0, stream>>>(pv, rv, basis, rr_part, rr_arr, k);
  }

  // preds = out0 + si*b + (sk-si)*(M a)
  k_matvec<<<dim3(20,10), 256, 0, stream>>>(Mmat, av, Ap_part, pAp_part);
  k_final <<<320,         256, 0, stream>>>(out0, bvec, Ap_part, lp, lsi, out);
}

// Round 2
// 552.239 us; speedup vs baseline: 1.0557x; 1.0557x over previous
//
#include <hip/hip_runtime.h>
#include <math.h>

#define BB    256      // batch
#define DIN   512
#define HD    512
#define DOUT  10
#define NS    32       // samples
#define NIDX  2560     // BB*DOUT
#define MAXIT 10
#define CG_EPS 1e-12f

// ---------------- reduction helper ----------------
__device__ __forceinline__ float wave_red(float v){
  #pragma unroll
  for (int off = 32; off > 0; off >>= 1) v += __shfl_down(v, off, 64);
  return v;  // lane 0 holds total
}

// ---------------- forward: h, G ----------------
// z = x @ W1 + b1 ; h = tanh(z) ; G = 1-h^2.  grid (8,4), 256 thr, 64x64 tile
__global__ __launch_bounds__(256) void k_gemm_z(
    const float* __restrict__ x, const float* __restrict__ W1,
    const float* __restrict__ b1, float* __restrict__ h, float* __restrict__ G)
{
  __shared__ __align__(16) float Al[16][68];
  __shared__ __align__(16) float Bl[16][64];
  const int tid = threadIdx.x;
  const int m0 = blockIdx.y * 64, n0 = blockIdx.x * 64;
  const int tx = tid & 15, ty = tid >> 4;
  float acc[4][4] = {};
  for (int k0 = 0; k0 < DIN; k0 += 16){
    {
      int m = tid >> 2, kk = (tid & 3) << 2;
      float4 a = *(const float4*)(x + (size_t)(m0+m)*DIN + k0 + kk);
      Al[kk+0][m]=a.x; Al[kk+1][m]=a.y; Al[kk+2][m]=a.z; Al[kk+3][m]=a.w;
    }
    {
      int kk = tid >> 4, n = (tid & 15) << 2;
      *(float4*)&Bl[kk][n] = *(const float4*)(W1 + (size_t)(k0+kk)*HD + n0 + n);
    }
    __syncthreads();
    #pragma unroll
    for (int kk = 0; kk < 16; kk++){
      float4 av = *(const float4*)&Al[kk][ty<<2];
      float4 bv = *(const float4*)&Bl[kk][tx<<2];
      float aa[4]={av.x,av.y,av.z,av.w}, bb[4]={bv.x,bv.y,bv.z,bv.w};
      #pragma unroll
      for (int i=0;i<4;i++)
        #pragma unroll
        for (int j=0;j<4;j++) acc[i][j] += aa[i]*bb[j];
    }
    __syncthreads();
  }
  float4 b4 = *(const float4*)&b1[n0 + (tx<<2)];
  float bbv[4] = {b4.x,b4.y,b4.z,b4.w};
  #pragma unroll
  for (int i=0;i<4;i++){
    int m = m0 + (ty<<2) + i;
    float hh[4], gg[4];
    #pragma unroll
    for (int j=0;j<4;j++){ float t = tanhf(acc[i][j] + bbv[j]); hh[j]=t; gg[j]=1.0f-t*t; }
    *(float4*)&h[(size_t)m*HD + n0 + (tx<<2)] = make_float4(hh[0],hh[1],hh[2],hh[3]);
    *(float4*)&G[(size_t)m*HD + n0 + (tx<<2)] = make_float4(gg[0],gg[1],gg[2],gg[3]);
  }
}

// ---------------- Kx = x x^T + 1 ; Kh = h h^T + 1 ----------------
__global__ __launch_bounds__(256) void k_gemm_kxkh(
    const float* __restrict__ x, const float* __restrict__ h,
    float* __restrict__ Kx, float* __restrict__ Kh)
{
  __shared__ __align__(16) float Al[16][68];
  __shared__ __align__(16) float Bl[16][68];
  const int tid = threadIdx.x;
  const float* A = blockIdx.z ? h : x;
  float* C = blockIdx.z ? Kh : Kx;
  const int m0 = blockIdx.y * 64, n0 = blockIdx.x * 64;
  const int tx = tid & 15, ty = tid >> 4;
  float acc[4][4] = {};
  for (int k0 = 0; k0 < DIN; k0 += 16){
    {
      int m = tid >> 2, kk = (tid & 3) << 2;
      float4 a = *(const float4*)(A + (size_t)(m0+m)*DIN + k0 + kk);
      Al[kk+0][m]=a.x; Al[kk+1][m]=a.y; Al[kk+2][m]=a.z; Al[kk+3][m]=a.w;
      float4 b = *(const float4*)(A + (size_t)(n0+m)*DIN + k0 + kk);
      Bl[kk+0][m]=b.x; Bl[kk+1][m]=b.y; Bl[kk+2][m]=b.z; Bl[kk+3][m]=b.w;
    }
    __syncthreads();
    #pragma unroll
    for (int kk = 0; kk < 16; kk++){
      float4 av = *(const float4*)&Al[kk][ty<<2];
      float4 bv = *(const float4*)&Bl[kk][tx<<2];
      float aa[4]={av.x,av.y,av.z,av.w}, bb[4]={bv.x,bv.y,bv.z,bv.w};
      #pragma unroll
      for (int i=0;i<4;i++)
        #pragma unroll
        for (int j=0;j<4;j++) acc[i][j] += aa[i]*bb[j];
    }
    __syncthreads();
  }
  #pragma unroll
  for (int i=0;i<4;i++){
    int m = m0 + (ty<<2) + i;
    *(float4*)&C[(size_t)m*BB + n0 + (tx<<2)] =
        make_float4(acc[i][0]+1.0f, acc[i][1]+1.0f, acc[i][2]+1.0f, acc[i][3]+1.0f);
  }
}

// ---------------- E[(b,o)][j] = G[b][j]*W2[j][o] ----------------
__global__ __launch_bounds__(256) void k_buildE(
    const float* __restrict__ G, const float* __restrict__ W2, float* __restrict__ E)
{
  int gid = blockIdx.x * 256 + threadIdx.x;   // 2560*128 lanes (f4 over j)
  int row = gid >> 7, j4 = (gid & 127) << 2;
  int b = row / 10, o = row - b * 10;
  float4 g = *(const float4*)&G[(size_t)b*HD + j4];
  *(float4*)&E[(size_t)row*HD + j4] = make_float4(
      g.x * W2[(j4+0)*DOUT + o], g.y * W2[(j4+1)*DOUT + o],
      g.z * W2[(j4+2)*DOUT + o], g.w * W2[(j4+3)*DOUT + o]);
}

// ---------------- M = Kx .* (E E^T) + delta_{oo'} Kh  (symmetric: upper tiles only) ----
// grid 820 = 40*41/2 upper-triangle 64x64 tiles. double-buffered, K-step 32.
__global__ __launch_bounds__(256) void k_gemm_M(
    const float* __restrict__ E, const float* __restrict__ Kx,
    const float* __restrict__ Kh, float* __restrict__ Mmat)
{
  __shared__ __align__(16) float Al[2][32][68];
  __shared__ __align__(16) float Bl[2][32][68];
  const int tid = threadIdx.x;
  int t = blockIdx.x, bi = 0;
  while (t >= 40 - bi){ t -= 40 - bi; bi++; }
  const int bj = bi + t;
  const int m0 = bi << 6, n0 = bj << 6;
  const int tx = tid & 15, ty = tid >> 4;
  const int sr = tid >> 3, sf = (tid & 7) << 2;   // staging: row, k-offset (it adds +32 rows)

  float4 ra[2], rb[2];
  // prologue load k0=0
  #pragma unroll
  for (int it = 0; it < 2; it++){
    int r = sr + (it << 5);
    ra[it] = *(const float4*)(E + (size_t)(m0+r)*HD + sf);
    rb[it] = *(const float4*)(E + (size_t)(n0+r)*HD + sf);
  }
  #pragma unroll
  for (int it = 0; it < 2; it++){
    int r = sr + (it << 5);
    Al[0][sf+0][r]=ra[it].x; Al[0][sf+1][r]=ra[it].y; Al[0][sf+2][r]=ra[it].z; Al[0][sf+3][r]=ra[it].w;
    Bl[0][sf+0][r]=rb[it].x; Bl[0][sf+1][r]=rb[it].y; Bl[0][sf+2][r]=rb[it].z; Bl[0][sf+3][r]=rb[it].w;
  }
  __syncthreads();

  float acc[4][4] = {};
  int cur = 0;
  for (int k0 = 0; k0 < HD; k0 += 32){
    const bool more = (k0 + 32 < HD);
    if (more){
      #pragma unroll
      for (int it = 0; it < 2; it++){
        int r = sr + (it << 5);
        ra[it] = *(const float4*)(E + (size_t)(m0+r)*HD + k0 + 32 + sf);
        rb[it] = *(const float4*)(E + (size_t)(n0+r)*HD + k0 + 32 + sf);
      }
    }
    #pragma unroll
    for (int kk = 0; kk < 32; kk++){
      float4 av = *(const float4*)&Al[cur][kk][ty<<2];
      float4 bv = *(const float4*)&Bl[cur][kk][tx<<2];
      float aa[4]={av.x,av.y,av.z,av.w}, bb[4]={bv.x,bv.y,bv.z,bv.w};
      #pragma unroll
      for (int i=0;i<4;i++)
        #pragma unroll
        for (int j=0;j<4;j++) acc[i][j] += aa[i]*bb[j];
    }
    if (more){
      int nb = cur ^ 1;
      #pragma unroll
      for (int it = 0; it < 2; it++){
        int r = sr + (it << 5);
        Al[nb][sf+0][r]=ra[it].x; Al[nb][sf+1][r]=ra[it].y; Al[nb][sf+2][r]=ra[it].z; Al[nb][sf+3][r]=ra[it].w;
        Bl[nb][sf+0][r]=rb[it].x; Bl[nb][sf+1][r]=rb[it].y; Bl[nb][sf+2][r]=rb[it].z; Bl[nb][sf+3][r]=rb[it].w;
      }
    }
    __syncthreads();
    cur ^= 1;
  }

  // epilogue: Hadamard Kx + diagonal Kh, write tile and (if off-diag) transposed tile
  int bm[4], om[4], bn[4], on[4];
  #pragma unroll
  for (int q=0;q<4;q++){
    int m = m0 + (ty<<2) + q; bm[q] = m/10; om[q] = m - bm[q]*10;
    int n = n0 + (tx<<2) + q; bn[q] = n/10; on[q] = n - bn[q]*10;
  }
  float v[4][4];
  #pragma unroll
  for (int i=0;i<4;i++)
    #pragma unroll
    for (int j=0;j<4;j++){
      float w = Kx[(size_t)bm[i]*BB + bn[j]] * acc[i][j];
      if (om[i] == on[j]) w += Kh[(size_t)bm[i]*BB + bn[j]];
      v[i][j] = w;
    }
  #pragma unroll
  for (int i=0;i<4;i++)
    *(float4*)&Mmat[(size_t)(m0+(ty<<2)+i)*NIDX + n0 + (tx<<2)] =
        make_float4(v[i][0],v[i][1],v[i][2],v[i][3]);
  if (bi != bj){
    #pragma unroll
    for (int j=0;j<4;j++)
      *(float4*)&Mmat[(size_t)(n0+(tx<<2)+j)*NIDX + m0 + (ty<<2)] =
          make_float4(v[0][j],v[1][j],v[2][j],v[3][j]);
  }
}

// ---------------- T[s] = (x @ eps_W1[s] + eps_b1[s]) * G ----------------
// tile 128m x 64n, K-step 16, double-buffered. grid 512 (2m x 8n x 32s), XCD-affine.
__global__ __launch_bounds__(256) void k_gemm_T(
    const float* __restrict__ x, const float* __restrict__ eW1,
    const float* __restrict__ eb1, const float* __restrict__ G,
    float* __restrict__ T)
{
  __shared__ __align__(16) float Al[2][16][132];
  __shared__ __align__(16) float Bl[2][16][68];
  const int tid = threadIdx.x;
  const int bid = blockIdx.x;
  const int xcd = bid & 7, q = bid >> 3;
  const int s   = xcd + ((q >> 4) << 3);
  const int rem = q & 15;
  const int nt = rem >> 1, mt = rem & 1;
  const int m0 = mt << 7, n0 = nt << 6;
  const float* Bsrc = eW1 + (size_t)s * DIN * HD;
  const int tx = tid & 15, ty = tid >> 4;
  const int sar = tid >> 2, saf = (tid & 3) << 2;   // A staging: rows tid>>2 (+64), k-f4
  const int sbk = tid >> 4, sbn = (tid & 15) << 2;  // B staging: k-row, n-f4

  float4 ra[2], rb;
  #pragma unroll
  for (int it = 0; it < 2; it++)
    ra[it] = *(const float4*)(x + (size_t)(m0 + sar + (it<<6))*DIN + saf);
  rb = *(const float4*)(Bsrc + (size_t)sbk*HD + n0 + sbn);
  #pragma unroll
  for (int it = 0; it < 2; it++){
    int r = sar + (it << 6);
    Al[0][saf+0][r]=ra[it].x; Al[0][saf+1][r]=ra[it].y; Al[0][saf+2][r]=ra[it].z; Al[0][saf+3][r]=ra[it].w;
  }
  *(float4*)&Bl[0][sbk][sbn] = rb;
  __syncthreads();

  float acc[2][4][4] = {};
  int cur = 0;
  for (int k0 = 0; k0 < DIN; k0 += 16){
    const bool more = (k0 + 16 < DIN);
    if (more){
      #pragma unroll
      for (int it = 0; it < 2; it++)
        ra[it] = *(const float4*)(x + (size_t)(m0 + sar + (it<<6))*DIN + k0 + 16 + saf);
      rb = *(const float4*)(Bsrc + (size_t)(k0 + 16 + sbk)*HD + n0 + sbn);
    }
    #pragma unroll
    for (int kk = 0; kk < 16; kk++){
      float4 a0 = *(const float4*)&Al[cur][kk][ty<<2];
      float4 a1 = *(const float4*)&Al[cur][kk][64 + (ty<<2)];
      float4 bv = *(const float4*)&Bl[cur][kk][tx<<2];
      float aa0[4]={a0.x,a0.y,a0.z,a0.w}, aa1[4]={a1.x,a1.y,a1.z,a1.w};
      float bb[4]={bv.x,bv.y,bv.z,bv.w};
      #pragma unroll
      for (int i=0;i<4;i++)
        #pragma unroll
        for (int j=0;j<4;j++){
          acc[0][i][j] += aa0[i]*bb[j];
          acc[1][i][j] += aa1[i]*bb[j];
        }
    }
    if (more){
      int nb = cur ^ 1;
      #pragma unroll
      for (int it = 0; it < 2; it++){
        int r = sar + (it << 6);
        Al[nb][saf+0][r]=ra[it].x; Al[nb][saf+1][r]=ra[it].y; Al[nb][saf+2][r]=ra[it].z; Al[nb][saf+3][r]=ra[it].w;
      }
      *(float4*)&Bl[nb][sbk][sbn] = rb;
    }
    __syncthreads();
    cur ^= 1;
  }

  float4 e4 = *(const float4*)&eb1[(size_t)s*HD + n0 + (tx<<2)];
  float eb[4] = {e4.x,e4.y,e4.z,e4.w};
  #pragma unroll
  for (int ia = 0; ia < 2; ia++)
    #pragma unroll
    for (int i = 0; i < 4; i++){
      int m = m0 + (ia<<6) + (ty<<2) + i;
      float4 g4 = *(const float4*)&G[(size_t)m*HD + n0 + (tx<<2)];
      float gg[4] = {g4.x,g4.y,g4.z,g4.w};
      float vv[4];
      #pragma unroll
      for (int j=0;j<4;j++) vv[j] = (acc[ia][i][j] + eb[j]) * gg[j];
      *(float4*)&T[((size_t)s*BB + m)*HD + n0 + (tx<<2)] = make_float4(vv[0],vv[1],vv[2],vv[3]);
    }
}

// ---------------- bvec (+ out0 for s==0 blocks) ----------------
// b_s = T[s] @ W2 + h @ eW2[s] + eb2[s]; W2/eW2 transposed in LDS.
__global__ __launch_bounds__(256) void k_bvec(
    const float* __restrict__ T, const float* __restrict__ W2,
    const float* __restrict__ h, const float* __restrict__ eW2,
    const float* __restrict__ eb2, const float* __restrict__ b2,
    float* __restrict__ bvec, float* __restrict__ out0, float* __restrict__ rr0_part)
{
  __shared__ __align__(16) float W2t[10][516];
  __shared__ __align__(16) float E2t[10][516];
  __shared__ float wl[4];
  const int tid = threadIdx.x, bid = blockIdx.x;
  const int s = bid / 10;
  const int idx = (bid % 10) * 256 + tid;
  const int b = idx / 10, o = idx - b*10;
  const float* e2 = eW2 + (size_t)s * HD * DOUT;
  for (int i = tid; i < HD*DOUT; i += 256){
    int k = i / 10, oo = i - k*10;
    W2t[oo][k] = W2[i];
    E2t[oo][k] = e2[i];
  }
  __syncthreads();
  const float* Tr = T + ((size_t)s*BB + b) * HD;
  const float* hr = h + (size_t)b * HD;
  const bool do0 = (bid < 10);
  float acc = eb2[s*DOUT + o];
  float a0 = 0.f;
  #pragma unroll 4
  for (int k4 = 0; k4 < HD/4; k4++){
    float4 t4 = *(const float4*)(Tr + (k4<<2));
    float4 h4 = *(const float4*)(hr + (k4<<2));
    float4 w4 = *(const float4*)&W2t[o][k4<<2];
    float4 q4 = *(const float4*)&E2t[o][k4<<2];
    acc += t4.x*w4.x + t4.y*w4.y + t4.z*w4.z + t4.w*w4.w
         + h4.x*q4.x + h4.y*q4.y + h4.z*q4.z + h4.w*q4.w;
    if (do0) a0 += h4.x*w4.x + h4.y*w4.y + h4.z*w4.z + h4.w*w4.w;
  }
  bvec[(size_t)s*NIDX + idx] = acc;
  if (do0) out0[idx] = a0 + b2[o];
  float v = wave_red(acc * acc);
  if ((tid & 63) == 0) wl[tid >> 6] = v;
  __syncthreads();
  if (tid == 0) rr0_part[bid] = wl[0]+wl[1]+wl[2]+wl[3];
}

// ---------------- CG init ----------------
__global__ __launch_bounds__(256) void k_init(
    const float* __restrict__ bvec, const float* __restrict__ rr0_part,
    float* __restrict__ r, float* __restrict__ p, float* __restrict__ a,
    float* __restrict__ basis, float* __restrict__ rr_arr)
{
  int gid = blockIdx.x * 256 + threadIdx.x;
  int s = gid / NIDX;
  float rr0 = 0.f;
  #pragma unroll
  for (int i = 0; i < 10; i++) rr0 += rr0_part[s*10 + i];
  float bv = bvec[gid];
  r[gid] = bv; p[gid] = bv; a[gid] = 0.f;
  basis[gid] = bv / (sqrtf(rr0) + CG_EPS);
  if (threadIdx.x == 0) rr_arr[s] = rr0;
}

// ---------------- matvec: Ap_part[kc] = M[:, Kchunk] @ p ; pAp block partials ----------------
// grid (20 row-tiles of 128, 10 K-chunks of 256)
__global__ __launch_bounds__(256) void k_matvec(
    const float* __restrict__ Mmat, const float* __restrict__ pv,
    float* __restrict__ Ap_part, float* __restrict__ pAp_part)
{
  __shared__ __align__(16) float Ml[32][132];
  __shared__ __align__(16) float Pl[32][36];
  __shared__ float sred[32][33];
  const int tid = threadIdx.x;
  const int rt = blockIdx.x, kc = blockIdx.y;
  const int R0 = rt * 128, K0 = kc * 256;
  const int tx = tid & 7, ty = tid >> 3;
  float acc[4][4] = {};
  for (int k0 = K0; k0 < K0 + 256; k0 += 32){
    #pragma unroll
    for (int it = 0; it < 4; it++){
      int id = tid + it * 256;
      int rr = id >> 3, f4 = id & 7;
      float4 mv = *(const float4*)(Mmat + (size_t)(R0+rr)*NIDX + k0 + (f4<<2));
      Ml[(f4<<2)+0][rr]=mv.x; Ml[(f4<<2)+1][rr]=mv.y; Ml[(f4<<2)+2][rr]=mv.z; Ml[(f4<<2)+3][rr]=mv.w;
    }
    {
      int s = tid >> 3, kf = (tid & 7) << 2;
      float4 pvv = *(const float4*)(pv + (size_t)s*NIDX + k0 + kf);
      Pl[kf+0][s]=pvv.x; Pl[kf+1][s]=pvv.y; Pl[kf+2][s]=pvv.z; Pl[kf+3][s]=pvv.w;
    }
    __syncthreads();
    #pragma unroll
    for (int kk = 0; kk < 32; kk++){
      float4 mv = *(const float4*)&Ml[kk][ty<<2];
      float4 pvv = *(const float4*)&Pl[kk][tx<<2];
      float mm[4]={mv.x,mv.y,mv.z,mv.w}, pp[4]={pvv.x,pvv.y,pvv.z,pvv.w};
      #pragma unroll
      for (int i=0;i<4;i++)
        #pragma unroll
        for (int j=0;j<4;j++) acc[i][j] += mm[i]*pp[j];
    }
    __syncthreads();
  }
  #pragma unroll
  for (int j = 0; j < 4; j++){
    int s = (tx<<2) + j;
    float4 pvv = *(const float4*)(pv + (size_t)s*NIDX + R0 + (ty<<2));
    float ps = acc[0][j]*pvv.x + acc[1][j]*pvv.y + acc[2][j]*pvv.z + acc[3][j]*pvv.w;
    *(float4*)&Ap_part[((size_t)kc*NS + s)*NIDX + R0 + (ty<<2)] =
        make_float4(acc[0][j], acc[1][j], acc[2][j], acc[3][j]);
    sred[ty][s] = ps;
  }
  __syncthreads();
  if (tid < 32){
    float v = 0.f;
    #pragma unroll
    for (int t = 0; t < 32; t++) v += sred[t][tid];
    pAp_part[(size_t)(kc*20 + rt)*NS + tid] = v;
  }
}

// ---------------- fused CG update (alpha, a/r, reortho, beta, p, basis) ----------------
// grid 32 (one block per sample), 256 threads; thread owns idx = tid + 256c, c<10
__global__ __launch_bounds__(256) void k_cg(
    const float* __restrict__ Ap_part, const float* __restrict__ pAp_part,
    float* __restrict__ rr_arr, int k,
    float* __restrict__ pv, float* __restrict__ av, float* __restrict__ rv,
    float* __restrict__ basis)
{
  __shared__ float wl[4];
  __shared__ float red[4][10];
  __shared__ float cbr[10];
  const int s = blockIdx.x, tid = threadIdx.x;
  const size_t base = (size_t)s * NIDX;
  const float rr = rr_arr[s];

  // pAp: reduce 200 block partials
  float v = (tid < 200) ? pAp_part[(size_t)tid*NS + s] : 0.f;
  v = wave_red(v);
  if ((tid & 63) == 0) wl[tid >> 6] = v;
  __syncthreads();
  const float pAp = wl[0]+wl[1]+wl[2]+wl[3];
  const float alpha = rr / (pAp + CG_EPS);

  float rn[10], pvv[10];
  #pragma unroll
  for (int c = 0; c < 10; c++){
    const int idx = tid + (c << 8);
    float ap = 0.f;
    #pragma unroll
    for (int kc = 0; kc < 10; kc++) ap += Ap_part[((size_t)kc*NS + s)*NIDX + idx];
    pvv[c] = pv[base + idx];
    av[base + idx] += alpha * pvv[c];
    rn[c] = rv[base + idx] - alpha * ap;
  }

  // Gram-Schmidt coefficients c_j = basis_j . r_new, j = 0..k  (rows >k are zero)
  for (int j = 0; j <= k; j++){
    float cv = 0.f;
    const float* brow = basis + (size_t)j * (NS*NIDX) + base;
    #pragma unroll
    for (int c = 0; c < 10; c++) cv += brow[tid + (c << 8)] * rn[c];
    cv = wave_red(cv);
    if ((tid & 63) == 0) red[tid >> 6][j] = cv;
  }
  __syncthreads();
  if (tid <= k) cbr[tid] = red[0][tid]+red[1][tid]+red[2][tid]+red[3][tid];
  __syncthreads();

  for (int j = 0; j <= k; j++){
    const float cc = cbr[j];
    const float* brow = basis + (size_t)j * (NS*NIDX) + base;
    #pragma unroll
    for (int c = 0; c < 10; c++) rn[c] -= brow[tid + (c << 8)] * cc;
  }

  float rr2 = 0.f;
  #pragma unroll
  for (int c = 0; c < 10; c++) rr2 += rn[c]*rn[c];
  rr2 = wave_red(rr2);
  __syncthreads();                       // protect wl reuse
  if ((tid & 63) == 0) wl[tid >> 6] = rr2;
  __syncthreads();
  const float rrn = wl[0]+wl[1]+wl[2]+wl[3];
  const float beta = rrn / (rr + CG_EPS);
  const float inv  = 1.0f / (sqrtf(rrn) + CG_EPS);

  float* bnew = basis + (size_t)(k+1) * (NS*NIDX) + base;
  #pragma unroll
  for (int c = 0; c < 10; c++){
    const int idx = tid + (c << 8);
    rv[base + idx] = rn[c];
    pv[base + idx] = rn[c] + beta * pvv[c];
    bnew[idx] = rn[c] * inv;
  }
  if (tid == 0) rr_arr[s] = rrn;
}

// ---------------- final: preds = out0 + si*b + (sk-si)*(M a) ----------------
__global__ __launch_bounds__(256) void k_final(
    const float* __restrict__ out0, const float* __restrict__ bvec,
    const float* __restrict__ Ma_part, const float* __restrict__ lp,
    const float* __restrict__ lsi, float* __restrict__ out)
{
  int gid = blockIdx.x * 256 + threadIdx.x;
  int s = gid / NIDX, idx = gid - s * NIDX;
  float sk = expf(-0.5f * lp[0]);
  float si = expf(lsi[0]);
  float ma = 0.f;
  #pragma unroll
  for (int kc = 0; kc < 10; kc++) ma += Ma_part[((size_t)kc*NS + s)*NIDX + idx];
  out[gid] = out0[idx] + si * bvec[gid] + (sk - si) * ma;
}

// ---------------- launch ----------------
extern "C" void kernel_launch(void* const* d_in, const int* in_sizes, int n_in,
                              void* d_out, int out_size, void* d_ws, size_t ws_size,
                              hipStream_t stream)
{
  const float* x   = (const float*)d_in[0];
  const float* W1  = (const float*)d_in[1];
  const float* b1  = (const float*)d_in[2];
  const float* W2  = (const float*)d_in[3];
  const float* b2  = (const float*)d_in[4];
  const float* eW1 = (const float*)d_in[5];
  const float* eb1 = (const float*)d_in[6];
  const float* eW2 = (const float*)d_in[7];
  const float* eb2 = (const float*)d_in[8];
  const float* lp  = (const float*)d_in[9];
  const float* lsi = (const float*)d_in[10];
  float* out = (float*)d_out;

  float* ws = (float*)d_ws;
  float* h        = ws;                       // 131072
  float* G        = h        + 131072;        // 131072
  float* Kx       = G        + 131072;        // 65536
  float* Kh       = Kx       + 65536;         // 65536
  float* E        = Kh       + 65536;         // 1310720
  float* Mmat     = E        + 1310720;       // 6553600
  float* T        = Mmat;                     // alias: T (4194304) dead before M is built
  float* out0     = Mmat     + 6553600;       // 2560
  float* bvec     = out0     + 2560;          // 81920
  float* rv       = bvec     + 81920;         // 81920
  float* pv       = rv       + 81920;         // 81920
  float* av       = pv       + 81920;         // 81920
  float* basis    = av       + 81920;         // 11*81920 = 901120
  float* Ap_part  = basis    + 901120;        // 10*81920 = 819200
  float* pAp_part = Ap_part  + 819200;        // 200*32 = 6400
  float* rr0_part = pAp_part + 6400;          // 320
  float* rr_arr   = rr0_part + 320;           // 32

  // setup
  k_gemm_z   <<<dim3(8,4),   256, 0, stream>>>(x, W1, b1, h, G);
  k_buildE   <<<1280,        256, 0, stream>>>(G, W2, E);
  k_gemm_kxkh<<<dim3(4,4,2), 256, 0, stream>>>(x, h, Kx, Kh);
  k_gemm_T   <<<512,         256, 0, stream>>>(x, eW1, eb1, G, T);
  k_bvec     <<<320,         256, 0, stream>>>(T, W2, h, eW2, eb2, b2, bvec, out0, rr0_part);
  k_gemm_M   <<<820,         256, 0, stream>>>(E, Kx, Kh, Mmat);  // overwrites T (dead)
  k_init     <<<320,         256, 0, stream>>>(bvec, rr0_part, rv, pv, av, basis, rr_arr);

  // 10 fixed CG steps with full reorthogonalization
  for (int k = 0; k < MAXIT; k++){
    k_matvec<<<dim3(20,10), 256, 0, stream>>>(Mmat, pv, Ap_part, pAp_part);
    k_cg    <<<NS,          256, 0, stream>>>(Ap_part, pAp_part, rr_arr, k, pv, av, rv, basis);
  }

  // preds = out0 + si*b + (sk-si)*(M a)
  k_matvec<<<dim3(20,10), 256, 0, stream>>>(Mmat, av, Ap_part, pAp_part);
  k_final <<<320,         256, 0, stream>>>(out0, bvec, Ap_part, lp, lsi, out);
}

// Round 3
// 505.224 us; speedup vs baseline: 1.1540x; 1.0931x over previous
//
#include <hip/hip_runtime.h>
#include <math.h>

#define BB    256      // batch
#define DIN   512
#define HD    512
#define DOUT  10
#define NS    32       // samples
#define NIDX  2560     // BB*DOUT
#define MAXIT 10
#define CG_EPS 1e-12f

typedef __attribute__((ext_vector_type(8))) short s16x8;   // 8 bf16 (4 VGPRs)
typedef __attribute__((ext_vector_type(4))) float f32x4;   // 4 fp32 acc

// ---------------- helpers ----------------
__device__ __forceinline__ float wave_red(float v){
  #pragma unroll
  for (int off = 32; off > 0; off >>= 1) v += __shfl_down(v, off, 64);
  return v;  // lane 0 holds total
}
__device__ __forceinline__ unsigned short f2bf(float f){
  unsigned u = __float_as_uint(f);
  return (unsigned short)((u + 0x7FFFu + ((u >> 16) & 1u)) >> 16);
}
__device__ __forceinline__ float bf2f(unsigned short h){
  return __uint_as_float((unsigned)h << 16);
}

// ---------------- forward: h, G ----------------
__global__ __launch_bounds__(256) void k_gemm_z(
    const float* __restrict__ x, const float* __restrict__ W1,
    const float* __restrict__ b1, float* __restrict__ h, float* __restrict__ G)
{
  __shared__ __align__(16) float Al[16][68];
  __shared__ __align__(16) float Bl[16][64];
  const int tid = threadIdx.x;
  const int m0 = blockIdx.y * 64, n0 = blockIdx.x * 64;
  const int tx = tid & 15, ty = tid >> 4;
  float acc[4][4] = {};
  for (int k0 = 0; k0 < DIN; k0 += 16){
    {
      int m = tid >> 2, kk = (tid & 3) << 2;
      float4 a = *(const float4*)(x + (size_t)(m0+m)*DIN + k0 + kk);
      Al[kk+0][m]=a.x; Al[kk+1][m]=a.y; Al[kk+2][m]=a.z; Al[kk+3][m]=a.w;
    }
    {
      int kk = tid >> 4, n = (tid & 15) << 2;
      *(float4*)&Bl[kk][n] = *(const float4*)(W1 + (size_t)(k0+kk)*HD + n0 + n);
    }
    __syncthreads();
    #pragma unroll
    for (int kk = 0; kk < 16; kk++){
      float4 av = *(const float4*)&Al[kk][ty<<2];
      float4 bv = *(const float4*)&Bl[kk][tx<<2];
      float aa[4]={av.x,av.y,av.z,av.w}, bb[4]={bv.x,bv.y,bv.z,bv.w};
      #pragma unroll
      for (int i=0;i<4;i++)
        #pragma unroll
        for (int j=0;j<4;j++) acc[i][j] += aa[i]*bb[j];
    }
    __syncthreads();
  }
  float4 b4 = *(const float4*)&b1[n0 + (tx<<2)];
  float bbv[4] = {b4.x,b4.y,b4.z,b4.w};
  #pragma unroll
  for (int i=0;i<4;i++){
    int m = m0 + (ty<<2) + i;
    float hh[4], gg[4];
    #pragma unroll
    for (int j=0;j<4;j++){ float t = tanhf(acc[i][j] + bbv[j]); hh[j]=t; gg[j]=1.0f-t*t; }
    *(float4*)&h[(size_t)m*HD + n0 + (tx<<2)] = make_float4(hh[0],hh[1],hh[2],hh[3]);
    *(float4*)&G[(size_t)m*HD + n0 + (tx<<2)] = make_float4(gg[0],gg[1],gg[2],gg[3]);
  }
}

// ---------------- Kx = x x^T + 1 ; Kh = h h^T + 1 ----------------
__global__ __launch_bounds__(256) void k_gemm_kxkh(
    const float* __restrict__ x, const float* __restrict__ h,
    float* __restrict__ Kx, float* __restrict__ Kh)
{
  __shared__ __align__(16) float Al[16][68];
  __shared__ __align__(16) float Bl[16][68];
  const int tid = threadIdx.x;
  const float* A = blockIdx.z ? h : x;
  float* C = blockIdx.z ? Kh : Kx;
  const int m0 = blockIdx.y * 64, n0 = blockIdx.x * 64;
  const int tx = tid & 15, ty = tid >> 4;
  float acc[4][4] = {};
  for (int k0 = 0; k0 < DIN; k0 += 16){
    {
      int m = tid >> 2, kk = (tid & 3) << 2;
      float4 a = *(const float4*)(A + (size_t)(m0+m)*DIN + k0 + kk);
      Al[kk+0][m]=a.x; Al[kk+1][m]=a.y; Al[kk+2][m]=a.z; Al[kk+3][m]=a.w;
      float4 b = *(const float4*)(A + (size_t)(n0+m)*DIN + k0 + kk);
      Bl[kk+0][m]=b.x; Bl[kk+1][m]=b.y; Bl[kk+2][m]=b.z; Bl[kk+3][m]=b.w;
    }
    __syncthreads();
    #pragma unroll
    for (int kk = 0; kk < 16; kk++){
      float4 av = *(const float4*)&Al[kk][ty<<2];
      float4 bv = *(const float4*)&Bl[kk][tx<<2];
      float aa[4]={av.x,av.y,av.z,av.w}, bb[4]={bv.x,bv.y,bv.z,bv.w};
      #pragma unroll
      for (int i=0;i<4;i++)
        #pragma unroll
        for (int j=0;j<4;j++) acc[i][j] += aa[i]*bb[j];
    }
    __syncthreads();
  }
  #pragma unroll
  for (int i=0;i<4;i++){
    int m = m0 + (ty<<2) + i;
    *(float4*)&C[(size_t)m*BB + n0 + (tx<<2)] =
        make_float4(acc[i][0]+1.0f, acc[i][1]+1.0f, acc[i][2]+1.0f, acc[i][3]+1.0f);
  }
}

// ---------------- E2 = [Ehi | Elo] bf16, E[(b,o)][j] = G[b][j]*W2[j][o] ----------------
__global__ __launch_bounds__(256) void k_buildE(
    const float* __restrict__ G, const float* __restrict__ W2,
    unsigned short* __restrict__ E2)
{
  int gid = blockIdx.x * 256 + threadIdx.x;   // 2560 rows * 128 j4-chunks
  int row = gid >> 7, j4 = (gid & 127) << 2;
  int b = row / 10, o = row - b * 10;
  float4 g = *(const float4*)&G[(size_t)b*HD + j4];
  float e[4] = { g.x * W2[(j4+0)*DOUT + o], g.y * W2[(j4+1)*DOUT + o],
                 g.z * W2[(j4+2)*DOUT + o], g.w * W2[(j4+3)*DOUT + o] };
  unsigned short hi[4], lo[4];
  #pragma unroll
  for (int r = 0; r < 4; r++){
    hi[r] = f2bf(e[r]);
    lo[r] = f2bf(e[r] - bf2f(hi[r]));
  }
  *(ushort4*)&E2[(size_t)row*1024 + j4]       = make_ushort4(hi[0],hi[1],hi[2],hi[3]);
  *(ushort4*)&E2[(size_t)row*1024 + 512 + j4] = make_ushort4(lo[0],lo[1],lo[2],lo[3]);
}

// ---------------- M = Kx .* (E E^T) + delta_{oo'} Kh  via split-bf16 MFMA ----------------
// 820 upper-tri 64x64 tiles, 1 wave/block. K-steps: 48 = 3 phases (hi*hi, hi*lo, lo*hi) x 16.
// Fragment layout (m89-verified): A row=lane&15, k=(lane>>4)*8+i ; C col=lane&15, row=(lane>>4)*4+reg.
__global__ void k_gemm_M(
    const unsigned short* __restrict__ E2, const float* __restrict__ Kx,
    const float* __restrict__ Kh, float* __restrict__ Mmat)
{
  const int tid = threadIdx.x;        // 0..63
  int t = blockIdx.x, bi = 0;
  while (t >= 40 - bi){ t -= 40 - bi; bi++; }
  const int bj = bi + t;
  const int m0 = bi << 6, n0 = bj << 6;
  const int ln = tid & 15, kq = tid >> 4;

  const unsigned short* pa[4];
  const unsigned short* pb[4];
  #pragma unroll
  for (int f = 0; f < 4; f++){
    pa[f] = E2 + (size_t)(m0 + f*16 + ln) * 1024 + kq * 8;
    pb[f] = E2 + (size_t)(n0 + f*16 + ln) * 1024 + kq * 8;
  }

  f32x4 acc[4][4];
  #pragma unroll
  for (int i = 0; i < 4; i++)
    #pragma unroll
    for (int j = 0; j < 4; j++)
      acc[i][j] = (f32x4){0.f, 0.f, 0.f, 0.f};

  s16x8 a0[4], b0[4], a1[4], b1[4];

  // step s in [0,48): phase = s>>4 in {0:hi*hi, 1:hi*lo, 2:lo*hi}; k0 = (s&15)*32
#define LOAD_AB(Aset, Bset, s) do{                                        \
    const int _ph = (s) >> 4, _kk = ((s) & 15) << 5;                      \
    const int _oa = (_ph == 2 ? 512 : 0) + _kk;                           \
    const int _ob = (_ph == 1 ? 512 : 0) + _kk;                           \
    Aset[0] = *(const s16x8*)(pa[0] + _oa);                               \
    Aset[1] = *(const s16x8*)(pa[1] + _oa);                               \
    Aset[2] = *(const s16x8*)(pa[2] + _oa);                               \
    Aset[3] = *(const s16x8*)(pa[3] + _oa);                               \
    Bset[0] = *(const s16x8*)(pb[0] + _ob);                               \
    Bset[1] = *(const s16x8*)(pb[1] + _ob);                               \
    Bset[2] = *(const s16x8*)(pb[2] + _ob);                               \
    Bset[3] = *(const s16x8*)(pb[3] + _ob);                               \
  }while(0)

#define MFMA_AB(Aset, Bset) do{                                           \
    _Pragma("unroll")                                                     \
    for (int fi = 0; fi < 4; fi++){                                       \
      _Pragma("unroll")                                                   \
      for (int fj = 0; fj < 4; fj++)                                      \
        acc[fi][fj] = __builtin_amdgcn_mfma_f32_16x16x32_bf16(            \
            Aset[fi], Bset[fj], acc[fi][fj], 0, 0, 0);                    \
    }                                                                     \
  }while(0)

  LOAD_AB(a0, b0, 0);
  for (int it = 0; it < 24; ++it){
    const int s1 = 2*it + 1;
    LOAD_AB(a1, b1, s1);
    MFMA_AB(a0, b0);
    const int s2 = 2*it + 2;
    if (s2 < 48) LOAD_AB(a0, b0, s2);
    MFMA_AB(a1, b1);
  }
#undef LOAD_AB
#undef MFMA_AB

  // epilogue: v = Kx[bm][bn]*acc + (om==on)*Kh[bm][bn]; write tile (+ transpose if off-diag)
  int bmv[4][4], omv[4][4], bnv[4], onv[4];
  #pragma unroll
  for (int f = 0; f < 4; f++){
    int n = n0 + f*16 + ln; bnv[f] = n / 10; onv[f] = n - bnv[f]*10;
    #pragma unroll
    for (int r = 0; r < 4; r++){
      int m = m0 + f*16 + kq*4 + r;
      bmv[f][r] = m / 10; omv[f][r] = m - bmv[f][r]*10;
    }
  }
  #pragma unroll
  for (int fi = 0; fi < 4; fi++)
    #pragma unroll
    for (int r = 0; r < 4; r++){
      const int m = m0 + fi*16 + kq*4 + r;
      #pragma unroll
      for (int fj = 0; fj < 4; fj++){
        const int n = n0 + fj*16 + ln;
        float v = Kx[(size_t)bmv[fi][r]*BB + bnv[fj]] * acc[fi][fj][r];
        if (omv[fi][r] == onv[fj]) v += Kh[(size_t)bmv[fi][r]*BB + bnv[fj]];
        Mmat[(size_t)m*NIDX + n] = v;
        if (bi != bj) Mmat[(size_t)n*NIDX + m] = v;
      }
    }
}

// ---------------- T[s] = (x @ eps_W1[s] + eps_b1[s]) * G ----------------
__global__ __launch_bounds__(256) void k_gemm_T(
    const float* __restrict__ x, const float* __restrict__ eW1,
    const float* __restrict__ eb1, const float* __restrict__ G,
    float* __restrict__ T)
{
  __shared__ __align__(16) float Al[2][16][132];
  __shared__ __align__(16) float Bl[2][16][68];
  const int tid = threadIdx.x;
  const int bid = blockIdx.x;
  const int xcd = bid & 7, q = bid >> 3;
  const int s   = xcd + ((q >> 4) << 3);
  const int rem = q & 15;
  const int nt = rem >> 1, mt = rem & 1;
  const int m0 = mt << 7, n0 = nt << 6;
  const float* Bsrc = eW1 + (size_t)s * DIN * HD;
  const int tx = tid & 15, ty = tid >> 4;
  const int sar = tid >> 2, saf = (tid & 3) << 2;
  const int sbk = tid >> 4, sbn = (tid & 15) << 2;

  float4 ra[2], rb;
  #pragma unroll
  for (int it = 0; it < 2; it++)
    ra[it] = *(const float4*)(x + (size_t)(m0 + sar + (it<<6))*DIN + saf);
  rb = *(const float4*)(Bsrc + (size_t)sbk*HD + n0 + sbn);
  #pragma unroll
  for (int it = 0; it < 2; it++){
    int r = sar + (it << 6);
    Al[0][saf+0][r]=ra[it].x; Al[0][saf+1][r]=ra[it].y; Al[0][saf+2][r]=ra[it].z; Al[0][saf+3][r]=ra[it].w;
  }
  *(float4*)&Bl[0][sbk][sbn] = rb;
  __syncthreads();

  float acc[2][4][4] = {};
  int cur = 0;
  for (int k0 = 0; k0 < DIN; k0 += 16){
    const bool more = (k0 + 16 < DIN);
    if (more){
      #pragma unroll
      for (int it = 0; it < 2; it++)
        ra[it] = *(const float4*)(x + (size_t)(m0 + sar + (it<<6))*DIN + k0 + 16 + saf);
      rb = *(const float4*)(Bsrc + (size_t)(k0 + 16 + sbk)*HD + n0 + sbn);
    }
    #pragma unroll
    for (int kk = 0; kk < 16; kk++){
      float4 a0 = *(const float4*)&Al[cur][kk][ty<<2];
      float4 a1 = *(const float4*)&Al[cur][kk][64 + (ty<<2)];
      float4 bv = *(const float4*)&Bl[cur][kk][tx<<2];
      float aa0[4]={a0.x,a0.y,a0.z,a0.w}, aa1[4]={a1.x,a1.y,a1.z,a1.w};
      float bb[4]={bv.x,bv.y,bv.z,bv.w};
      #pragma unroll
      for (int i=0;i<4;i++)
        #pragma unroll
        for (int j=0;j<4;j++){
          acc[0][i][j] += aa0[i]*bb[j];
          acc[1][i][j] += aa1[i]*bb[j];
        }
    }
    if (more){
      int nb = cur ^ 1;
      #pragma unroll
      for (int it = 0; it < 2; it++){
        int r = sar + (it << 6);
        Al[nb][saf+0][r]=ra[it].x; Al[nb][saf+1][r]=ra[it].y; Al[nb][saf+2][r]=ra[it].z; Al[nb][saf+3][r]=ra[it].w;
      }
      *(float4*)&Bl[nb][sbk][sbn] = rb;
    }
    __syncthreads();
    cur ^= 1;
  }

  float4 e4 = *(const float4*)&eb1[(size_t)s*HD + n0 + (tx<<2)];
  float eb[4] = {e4.x,e4.y,e4.z,e4.w};
  #pragma unroll
  for (int ia = 0; ia < 2; ia++)
    #pragma unroll
    for (int i = 0; i < 4; i++){
      int m = m0 + (ia<<6) + (ty<<2) + i;
      float4 g4 = *(const float4*)&G[(size_t)m*HD + n0 + (tx<<2)];
      float gg[4] = {g4.x,g4.y,g4.z,g4.w};
      float vv[4];
      #pragma unroll
      for (int j=0;j<4;j++) vv[j] = (acc[ia][i][j] + eb[j]) * gg[j];
      *(float4*)&T[((size_t)s*BB + m)*HD + n0 + (tx<<2)] = make_float4(vv[0],vv[1],vv[2],vv[3]);
    }
}

// ---------------- bvec (+ out0 for s==0 blocks) ----------------
__global__ __launch_bounds__(256) void k_bvec(
    const float* __restrict__ T, const float* __restrict__ W2,
    const float* __restrict__ h, const float* __restrict__ eW2,
    const float* __restrict__ eb2, const float* __restrict__ b2,
    float* __restrict__ bvec, float* __restrict__ out0, float* __restrict__ rr0_part)
{
  __shared__ __align__(16) float W2t[10][516];
  __shared__ __align__(16) float E2t[10][516];
  __shared__ float wl[4];
  const int tid = threadIdx.x, bid = blockIdx.x;
  const int s = bid / 10;
  const int idx = (bid % 10) * 256 + tid;
  const int b = idx / 10, o = idx - b*10;
  const float* e2 = eW2 + (size_t)s * HD * DOUT;
  for (int i = tid; i < HD*DOUT; i += 256){
    int k = i / 10, oo = i - k*10;
    W2t[oo][k] = W2[i];
    E2t[oo][k] = e2[i];
  }
  __syncthreads();
  const float* Tr = T + ((size_t)s*BB + b) * HD;
  const float* hr = h + (size_t)b * HD;
  const bool do0 = (bid < 10);
  float acc = eb2[s*DOUT + o];
  float a0 = 0.f;
  #pragma unroll 4
  for (int k4 = 0; k4 < HD/4; k4++){
    float4 t4 = *(const float4*)(Tr + (k4<<2));
    float4 h4 = *(const float4*)(hr + (k4<<2));
    float4 w4 = *(const float4*)&W2t[o][k4<<2];
    float4 q4 = *(const float4*)&E2t[o][k4<<2];
    acc += t4.x*w4.x + t4.y*w4.y + t4.z*w4.z + t4.w*w4.w
         + h4.x*q4.x + h4.y*q4.y + h4.z*q4.z + h4.w*q4.w;
    if (do0) a0 += h4.x*w4.x + h4.y*w4.y + h4.z*w4.z + h4.w*w4.w;
  }
  bvec[(size_t)s*NIDX + idx] = acc;
  if (do0) out0[idx] = a0 + b2[o];
  float v = wave_red(acc * acc);
  if ((tid & 63) == 0) wl[tid >> 6] = v;
  __syncthreads();
  if (tid == 0) rr0_part[bid] = wl[0]+wl[1]+wl[2]+wl[3];
}

// ---------------- CG init ----------------
__global__ __launch_bounds__(256) void k_init(
    const float* __restrict__ bvec, const float* __restrict__ rr0_part,
    float* __restrict__ r, float* __restrict__ p, float* __restrict__ a,
    float* __restrict__ basis, float* __restrict__ rr_arr)
{
  int gid = blockIdx.x * 256 + threadIdx.x;
  int s = gid / NIDX;
  float rr0 = 0.f;
  #pragma unroll
  for (int i = 0; i < 10; i++) rr0 += rr0_part[s*10 + i];
  float bv = bvec[gid];
  r[gid] = bv; p[gid] = bv; a[gid] = 0.f;
  basis[gid] = bv / (sqrtf(rr0) + CG_EPS);
  if (threadIdx.x == 0) rr_arr[s] = rr0;
}

// ---------------- matvec: Ap_part[kc] = M[:, Kchunk] @ p ; pAp block partials ----------------
__global__ __launch_bounds__(256) void k_matvec(
    const float* __restrict__ Mmat, const float* __restrict__ pv,
    float* __restrict__ Ap_part, float* __restrict__ pAp_part)
{
  __shared__ __align__(16) float Ml[32][132];
  __shared__ __align__(16) float Pl[32][36];
  __shared__ float sred[32][33];
  const int tid = threadIdx.x;
  const int rt = blockIdx.x, kc = blockIdx.y;
  const int R0 = rt * 128, K0 = kc * 256;
  const int tx = tid & 7, ty = tid >> 3;
  float acc[4][4] = {};
  for (int k0 = K0; k0 < K0 + 256; k0 += 32){
    #pragma unroll
    for (int it = 0; it < 4; it++){
      int id = tid + it * 256;
      int rr = id >> 3, f4 = id & 7;
      float4 mv = *(const float4*)(Mmat + (size_t)(R0+rr)*NIDX + k0 + (f4<<2));
      Ml[(f4<<2)+0][rr]=mv.x; Ml[(f4<<2)+1][rr]=mv.y; Ml[(f4<<2)+2][rr]=mv.z; Ml[(f4<<2)+3][rr]=mv.w;
    }
    {
      int s = tid >> 3, kf = (tid & 7) << 2;
      float4 pvv = *(const float4*)(pv + (size_t)s*NIDX + k0 + kf);
      Pl[kf+0][s]=pvv.x; Pl[kf+1][s]=pvv.y; Pl[kf+2][s]=pvv.z; Pl[kf+3][s]=pvv.w;
    }
    __syncthreads();
    #pragma unroll
    for (int kk = 0; kk < 32; kk++){
      float4 mv = *(const float4*)&Ml[kk][ty<<2];
      float4 pvv = *(const float4*)&Pl[kk][tx<<2];
      float mm[4]={mv.x,mv.y,mv.z,mv.w}, pp[4]={pvv.x,pvv.y,pvv.z,pvv.w};
      #pragma unroll
      for (int i=0;i<4;i++)
        #pragma unroll
        for (int j=0;j<4;j++) acc[i][j] += mm[i]*pp[j];
    }
    __syncthreads();
  }
  #pragma unroll
  for (int j = 0; j < 4; j++){
    int s = (tx<<2) + j;
    float4 pvv = *(const float4*)(pv + (size_t)s*NIDX + R0 + (ty<<2));
    float ps = acc[0][j]*pvv.x + acc[1][j]*pvv.y + acc[2][j]*pvv.z + acc[3][j]*pvv.w;
    *(float4*)&Ap_part[((size_t)kc*NS + s)*NIDX + R0 + (ty<<2)] =
        make_float4(acc[0][j], acc[1][j], acc[2][j], acc[3][j]);
    sred[ty][s] = ps;
  }
  __syncthreads();
  if (tid < 32){
    float v = 0.f;
    #pragma unroll
    for (int t = 0; t < 32; t++) v += sred[t][tid];
    pAp_part[(size_t)(kc*20 + rt)*NS + tid] = v;
  }
}

// ---------------- fused CG update ----------------
__global__ __launch_bounds__(256) void k_cg(
    const float* __restrict__ Ap_part, const float* __restrict__ pAp_part,
    float* __restrict__ rr_arr, int k,
    float* __restrict__ pv, float* __restrict__ av, float* __restrict__ rv,
    float* __restrict__ basis)
{
  __shared__ float wl[4];
  __shared__ float red[4][10];
  __shared__ float cbr[10];
  const int s = blockIdx.x, tid = threadIdx.x;
  const size_t base = (size_t)s * NIDX;
  const float rr = rr_arr[s];

  float v = (tid < 200) ? pAp_part[(size_t)tid*NS + s] : 0.f;
  v = wave_red(v);
  if ((tid & 63) == 0) wl[tid >> 6] = v;
  __syncthreads();
  const float pAp = wl[0]+wl[1]+wl[2]+wl[3];
  const float alpha = rr / (pAp + CG_EPS);

  float rn[10], pvv[10];
  #pragma unroll
  for (int c = 0; c < 10; c++){
    const int idx = tid + (c << 8);
    float ap = 0.f;
    #pragma unroll
    for (int kc = 0; kc < 10; kc++) ap += Ap_part[((size_t)kc*NS + s)*NIDX + idx];
    pvv[c] = pv[base + idx];
    av[base + idx] += alpha * pvv[c];
    rn[c] = rv[base + idx] - alpha * ap;
  }

  for (int j = 0; j <= k; j++){
    float cv = 0.f;
    const float* brow = basis + (size_t)j * (NS*NIDX) + base;
    #pragma unroll
    for (int c = 0; c < 10; c++) cv += brow[tid + (c << 8)] * rn[c];
    cv = wave_red(cv);
    if ((tid & 63) == 0) red[tid >> 6][j] = cv;
  }
  __syncthreads();
  if (tid <= k) cbr[tid] = red[0][tid]+red[1][tid]+red[2][tid]+red[3][tid];
  __syncthreads();

  for (int j = 0; j <= k; j++){
    const float cc = cbr[j];
    const float* brow = basis + (size_t)j * (NS*NIDX) + base;
    #pragma unroll
    for (int c = 0; c < 10; c++) rn[c] -= brow[tid + (c << 8)] * cc;
  }

  float rr2 = 0.f;
  #pragma unroll
  for (int c = 0; c < 10; c++) rr2 += rn[c]*rn[c];
  rr2 = wave_red(rr2);
  __syncthreads();
  if ((tid & 63) == 0) wl[tid >> 6] = rr2;
  __syncthreads();
  const float rrn = wl[0]+wl[1]+wl[2]+wl[3];
  const float beta = rrn / (rr + CG_EPS);
  const float inv  = 1.0f / (sqrtf(rrn) + CG_EPS);

  float* bnew = basis + (size_t)(k+1) * (NS*NIDX) + base;
  #pragma unroll
  for (int c = 0; c < 10; c++){
    const int idx = tid + (c << 8);
    rv[base + idx] = rn[c];
    pv[base + idx] = rn[c] + beta * pvv[c];
    bnew[idx] = rn[c] * inv;
  }
  if (tid == 0) rr_arr[s] = rrn;
}

// ---------------- final: preds = out0 + si*b + (sk-si)*(M a) ----------------
__global__ __launch_bounds__(256) void k_final(
    const float* __restrict__ out0, const float* __restrict__ bvec,
    const float* __restrict__ Ma_part, const float* __restrict__ lp,
    const float* __restrict__ lsi, float* __restrict__ out)
{
  int gid = blockIdx.x * 256 + threadIdx.x;
  int s = gid / NIDX, idx = gid - s * NIDX;
  float sk = expf(-0.5f * lp[0]);
  float si = expf(lsi[0]);
  float ma = 0.f;
  #pragma unroll
  for (int kc = 0; kc < 10; kc++) ma += Ma_part[((size_t)kc*NS + s)*NIDX + idx];
  out[gid] = out0[idx] + si * bvec[gid] + (sk - si) * ma;
}

// ---------------- launch ----------------
extern "C" void kernel_launch(void* const* d_in, const int* in_sizes, int n_in,
                              void* d_out, int out_size, void* d_ws, size_t ws_size,
                              hipStream_t stream)
{
  const float* x   = (const float*)d_in[0];
  const float* W1  = (const float*)d_in[1];
  const float* b1  = (const float*)d_in[2];
  const float* W2  = (const float*)d_in[3];
  const float* b2  = (const float*)d_in[4];
  const float* eW1 = (const float*)d_in[5];
  const float* eb1 = (const float*)d_in[6];
  const float* eW2 = (const float*)d_in[7];
  const float* eb2 = (const float*)d_in[8];
  const float* lp  = (const float*)d_in[9];
  const float* lsi = (const float*)d_in[10];
  float* out = (float*)d_out;

  float* ws = (float*)d_ws;
  float* h        = ws;                       // 131072
  float* G        = h        + 131072;        // 131072
  float* Kx       = G        + 131072;        // 65536
  float* Kh       = Kx       + 65536;         // 65536
  float* Ereg     = Kh       + 65536;         // 1310720 floats = E2 (2560x1024 bf16 hi|lo)
  unsigned short* E2 = (unsigned short*)Ereg;
  float* Mmat     = Ereg     + 1310720;       // 6553600
  float* T        = Mmat;                     // alias: T (4194304) dead before M is built
  float* out0     = Mmat     + 6553600;       // 2560
  float* bvec     = out0     + 2560;          // 81920
  float* rv       = bvec     + 81920;         // 81920
  float* pv       = rv       + 81920;         // 81920
  float* av       = pv       + 81920;         // 81920
  float* basis    = av       + 81920;         // 11*81920 = 901120
  float* Ap_part  = basis    + 901120;        // 10*81920 = 819200
  float* pAp_part = Ap_part  + 819200;        // 200*32 = 6400
  float* rr0_part = pAp_part + 6400;          // 320
  float* rr_arr   = rr0_part + 320;           // 32

  // setup
  k_gemm_z   <<<dim3(8,4),   256, 0, stream>>>(x, W1, b1, h, G);
  k_buildE   <<<1280,        256, 0, stream>>>(G, W2, E2);
  k_gemm_kxkh<<<dim3(4,4,2), 256, 0, stream>>>(x, h, Kx, Kh);
  k_gemm_T   <<<512,         256, 0, stream>>>(x, eW1, eb1, G, T);
  k_bvec     <<<320,         256, 0, stream>>>(T, W2, h, eW2, eb2, b2, bvec, out0, rr0_part);
  k_gemm_M   <<<820,         64,  0, stream>>>(E2, Kx, Kh, Mmat);  // overwrites T (dead)
  k_init     <<<320,         256, 0, stream>>>(bvec, rr0_part, rv, pv, av, basis, rr_arr);

  // 10 fixed CG steps with full reorthogonalization
  for (int k = 0; k < MAXIT; k++){
    k_matvec<<<dim3(20,10), 256, 0, stream>>>(Mmat, pv, Ap_part, pAp_part);
    k_cg    <<<NS,          256, 0, stream>>>(Ap_part, pAp_part, rr_arr, k, pv, av, rv, basis);
  }

  // preds = out0 + si*b + (sk-si)*(M a)
  k_matvec<<<dim3(20,10), 256, 0, stream>>>(Mmat, av, Ap_part, pAp_part);
  k_final <<<320,         256, 0, stream>>>(out0, bvec, Ap_part, lp, lsi, out);
}